// Round 1
// baseline (6494.910 us; speedup 1.0000x reference)
//
#include <hip/hip_runtime.h>
#include <hip/hip_bf16.h>
#include <cstdint>
#include <cstddef>

// Problem constants
#define NBLK   12
#define EMBED  1024
#define SEQT   257          // tokens incl CLS
#define BATCH  32
#define NHEADS 16
#define HD     64
#define HIDF   2816
#define MV     (BATCH*SEQT) // 8224 valid rows
#define MPAD   8320         // 65*128
#define SP     288          // padded seq for attention (9*32)

typedef __attribute__((ext_vector_type(8))) short short8;
typedef __attribute__((ext_vector_type(4))) float f32x4;

__device__ __forceinline__ short f2bs(float f) {
  unsigned u = __float_as_uint(f);
  unsigned r = (u + 0x7fffu + ((u >> 16) & 1u)) >> 16;
  return (short)r;
}
__device__ __forceinline__ float bs2f(short s) {
  return __uint_as_float(((unsigned)(unsigned short)s) << 16);
}

__device__ __forceinline__ void async_copy16(void* lds, const void* g) {
  __builtin_amdgcn_global_load_lds(
      (const __attribute__((address_space(1))) unsigned int*)g,
      (__attribute__((address_space(3))) unsigned int*)lds,
      16, 0, 0);
}

// ---------------------------------------------------------------------------
// Generic bf16 GEMM, A [M][K] row-major, B^T [N][K] row-major, 128x128 tile,
// BK=64, 4 waves each computing 64x64 via 4x4 grid of 16x16x32 MFMAs.
// MODE 0: store bf16; 1: store f32; 2: f32 + residual add; 3: silu(C)*Aux bf16
// ---------------------------------------------------------------------------
template<int MODE>
__global__ __launch_bounds__(256, 2)
void gemm_bt(const short* __restrict__ A, const short* __restrict__ B,
             void* __restrict__ Out, const float* __restrict__ Resid,
             const short* __restrict__ Aux,
             int M, int N, int K, int Mvalid)
{
  __shared__ short sA[128 * 64];
  __shared__ short sB[128 * 64];
  const int tid  = threadIdx.x;
  const int wid  = tid >> 6;
  const int lane = tid & 63;
  const int r16  = lane & 15;
  const int quad = lane >> 4;
  const int m0 = blockIdx.y * 128;
  const int n0 = blockIdx.x * 128;
  const int wm = (wid >> 1) * 64;
  const int wn = (wid & 1) * 64;

  f32x4 acc[4][4];
#pragma unroll
  for (int i = 0; i < 4; ++i)
#pragma unroll
    for (int j = 0; j < 4; ++j)
      acc[i][j] = (f32x4){0.f, 0.f, 0.f, 0.f};

  const int nk = K >> 6;
  for (int kt = 0; kt < nk; ++kt) {
    const int k0 = kt << 6;
    __syncthreads();   // all waves done reading previous tile
#pragma unroll
    for (int i = 0; i < 4; ++i) {
      const int c   = wid * 256 + i * 64;   // wave-uniform chunk base
      const int cl  = c + lane;             // this lane's 16B chunk
      const int row = cl >> 3;              // 8 chunks per 64-elem row
      const int col = (cl & 7) << 3;
      async_copy16(&sA[c * 8], A + (size_t)(m0 + row) * K + k0 + col);
      async_copy16(&sB[c * 8], B + (size_t)(n0 + row) * K + k0 + col);
    }
    asm volatile("s_waitcnt vmcnt(0)" ::: "memory");
    __syncthreads();
#pragma unroll
    for (int ks = 0; ks < 2; ++ks) {
      short8 af[4], bf[4];
#pragma unroll
      for (int t = 0; t < 4; ++t) {
        af[t] = *(const short8*)&sA[(wm + t * 16 + r16) * 64 + ks * 32 + quad * 8];
        bf[t] = *(const short8*)&sB[(wn + t * 16 + r16) * 64 + ks * 32 + quad * 8];
      }
#pragma unroll
      for (int i = 0; i < 4; ++i)
#pragma unroll
        for (int j = 0; j < 4; ++j)
          acc[i][j] = __builtin_amdgcn_mfma_f32_16x16x32_bf16(af[i], bf[j], acc[i][j], 0, 0, 0);
    }
  }

#pragma unroll
  for (int i = 0; i < 4; ++i) {
#pragma unroll
    for (int r = 0; r < 4; ++r) {
      const int row = m0 + wm + i * 16 + quad * 4 + r;
      if (row >= Mvalid) continue;
#pragma unroll
      for (int j = 0; j < 4; ++j) {
        const int col = n0 + wn + j * 16 + r16;
        const size_t idx = (size_t)row * N + col;
        const float v = acc[i][j][r];
        if (MODE == 0) {
          ((short*)Out)[idx] = f2bs(v);
        } else if (MODE == 1) {
          ((float*)Out)[idx] = v;
        } else if (MODE == 2) {
          ((float*)Out)[idx] = v + Resid[idx];
        } else {
          const float u3 = bs2f(Aux[idx]);
          const float sig = 1.f / (1.f + __expf(-v));
          ((short*)Out)[idx] = f2bs(v * sig * u3);
        }
      }
    }
  }
}

// ---------------------------------------------------------------------------
// fp32 [K][N] -> bf16 [N][K] transpose+cast (32x32 LDS tile)
// ---------------------------------------------------------------------------
__global__ void transpose_cast(const float* __restrict__ src, short* __restrict__ dst,
                               int K, int N)
{
  __shared__ float t[32][33];
  const int n0 = blockIdx.x * 32;
  const int k0 = blockIdx.y * 32;
  const int tx = threadIdx.x;
  const int ty = threadIdx.y;  // 0..7
#pragma unroll
  for (int i = 0; i < 32; i += 8)
    t[ty + i][tx] = src[(size_t)(k0 + ty + i) * N + n0 + tx];
  __syncthreads();
#pragma unroll
  for (int i = 0; i < 32; i += 8)
    dst[(size_t)(n0 + ty + i) * K + k0 + tx] = f2bs(t[tx][ty + i]);
}

__global__ void cast_bf16(const float* __restrict__ src, short* __restrict__ dst, int n)
{
  const int i = blockIdx.x * 256 + threadIdx.x;
  if (i < n) dst[i] = f2bs(src[i]);
}

// ---------------------------------------------------------------------------
// RoPE cos/sin table: fc[s][j][0/1], s in [0,257), j in [0,32). s=0 -> zeros.
// ---------------------------------------------------------------------------
__global__ void freqs_k(float* __restrict__ fc)
{
  const int idx = blockIdx.x * 256 + threadIdx.x;
  if (idx >= SEQT * 32) return;
  const int s = idx >> 5;
  const int j = idx & 31;
  float c = 0.f, sn = 0.f;
  if (s != 0) {
    const int p = s - 1;
    const int pos = (j < 16) ? (p >> 4) : (p & 15);
    const int fi = (j < 16) ? j : (j - 16);
    const float fr = __powf(10000.f, -(float)fi / 16.f);
    const float ang = (float)pos * fr;
    c = cosf(ang); sn = sinf(ang);
  }
  fc[idx * 2]     = c;
  fc[idx * 2 + 1] = sn;
}

// ---------------------------------------------------------------------------
// cond embed: c[b][o] = cond[b] . cond_w[:,o] + cond_b[o]   (fp32 exact)
// ---------------------------------------------------------------------------
__global__ void cond_embed_k(const float* __restrict__ cond, const float* __restrict__ w,
                             const float* __restrict__ bias, float* __restrict__ out)
{
  const int b = blockIdx.y;
  const int o = blockIdx.x * 256 + threadIdx.x;
  const float* cr = cond + (size_t)b * EMBED;
  float acc = 0.f;
  for (int in = 0; in < 1024; ++in)
    acc += cr[in] * w[(size_t)in * EMBED + o];
  out[(size_t)b * EMBED + o] = acc + bias[o];
}

// ---------------------------------------------------------------------------
// Assemble token row (cond token / patch+bias) + pos_embed, then LayerNorm.
// One block per row, 256 threads x 4 elems.
// ---------------------------------------------------------------------------
__global__ void assemble_ln_k(const float* __restrict__ tmp, const float* __restrict__ cemb,
                              const float* __restrict__ pb, const float* __restrict__ pos,
                              const float* __restrict__ g, const float* __restrict__ beta,
                              float* __restrict__ h)
{
  const int r = blockIdx.x;
  const int bb = r / SEQT;
  const int s = r % SEQT;
  const int t = threadIdx.x;
  float4 v;
  if (s == 0) {
    v = ((const float4*)(cemb + (size_t)bb * EMBED))[t];
  } else {
    v = ((const float4*)(tmp + (size_t)(bb * 256 + s - 1) * EMBED))[t];
    const float4 pb4 = ((const float4*)pb)[t];
    v.x += pb4.x; v.y += pb4.y; v.z += pb4.z; v.w += pb4.w;
  }
  const float4 p4 = ((const float4*)(pos + (size_t)s * EMBED))[t];
  v.x += p4.x; v.y += p4.y; v.z += p4.z; v.w += p4.w;

  float s1 = v.x + v.y + v.z + v.w;
  float s2 = v.x * v.x + v.y * v.y + v.z * v.z + v.w * v.w;
  __shared__ float sb[8];
  const int lane = t & 63, wid = t >> 6;
#pragma unroll
  for (int off = 32; off > 0; off >>= 1) {
    s1 += __shfl_down(s1, off, 64);
    s2 += __shfl_down(s2, off, 64);
  }
  if (lane == 0) { sb[wid] = s1; sb[4 + wid] = s2; }
  __syncthreads();
  const float tot   = sb[0] + sb[1] + sb[2] + sb[3];
  const float totsq = sb[4] + sb[5] + sb[6] + sb[7];
  const float mean = tot * (1.f / 1024.f);
  const float var  = totsq * (1.f / 1024.f) - mean * mean;
  const float sc = rsqrtf(var + 1e-6f);
  const float4 g4 = ((const float4*)g)[t];
  const float4 be4 = ((const float4*)beta)[t];
  float4 o;
  o.x = (v.x - mean) * sc * g4.x + be4.x;
  o.y = (v.y - mean) * sc * g4.y + be4.y;
  o.z = (v.z - mean) * sc * g4.z + be4.z;
  o.w = (v.w - mean) * sc * g4.w + be4.w;
  ((float4*)(h + (size_t)r * EMBED))[t] = o;
}

// ---------------------------------------------------------------------------
// RMSNorm fp32 row -> bf16 (x * rsqrt(mean(x^2)+eps)) * w
// ---------------------------------------------------------------------------
__global__ void rmsnorm_k(const float* __restrict__ h, const float* __restrict__ w,
                          short* __restrict__ out)
{
  const int r = blockIdx.x;
  const int t = threadIdx.x;
  const float4 v = ((const float4*)(h + (size_t)r * EMBED))[t];
  float ss = v.x * v.x + v.y * v.y + v.z * v.z + v.w * v.w;
  __shared__ float sb[4];
  const int lane = t & 63, wid = t >> 6;
#pragma unroll
  for (int off = 32; off > 0; off >>= 1) ss += __shfl_down(ss, off, 64);
  if (lane == 0) sb[wid] = ss;
  __syncthreads();
  const float tot = sb[0] + sb[1] + sb[2] + sb[3];
  const float sc = rsqrtf(tot * (1.f / 1024.f) + 1e-5f);
  const float4 w4 = ((const float4*)w)[t];
  short* op = out + (size_t)r * EMBED + t * 4;
  op[0] = f2bs(v.x * sc * w4.x);
  op[1] = f2bs(v.y * sc * w4.y);
  op[2] = f2bs(v.z * sc * w4.z);
  op[3] = f2bs(v.w * sc * w4.w);
}

// ---------------------------------------------------------------------------
// RoPE + scatter into per-head Q [bh][SP][64], K [bh][SP][64], V^T [bh][64][SP]
// ---------------------------------------------------------------------------
__global__ void rope_k(const short* __restrict__ qkv, const float* __restrict__ fc,
                       short* __restrict__ Q, short* __restrict__ Kt, short* __restrict__ Vt)
{
  const int r = blockIdx.x;
  const int bb = r / SEQT;
  const int s = r % SEQT;
  const int t = threadIdx.x;
  const short* row = qkv + (size_t)r * 3072;
#pragma unroll
  for (int ii = 0; ii < 2; ++ii) {
    const int i = t + ii * 256;        // 512 (head,pair) combos
    const int hh = i >> 5;
    const int j = i & 31;
    const float cs = fc[(s * 32 + j) * 2];
    const float sn = fc[(s * 32 + j) * 2 + 1];
    const size_t ob = (((size_t)bb * NHEADS + hh) * SP + s) * HD + 2 * j;
    {
      const float x0 = bs2f(row[hh * HD + 2 * j]);
      const float x1 = bs2f(row[hh * HD + 2 * j + 1]);
      Q[ob]     = f2bs(x0 * cs - x1 * sn);
      Q[ob + 1] = f2bs(x1 * cs + x0 * sn);
    }
    {
      const float x0 = bs2f(row[EMBED + hh * HD + 2 * j]);
      const float x1 = bs2f(row[EMBED + hh * HD + 2 * j + 1]);
      Kt[ob]     = f2bs(x0 * cs - x1 * sn);
      Kt[ob + 1] = f2bs(x1 * cs + x0 * sn);
    }
  }
#pragma unroll
  for (int ii = 0; ii < 4; ++ii) {
    const int i = t + ii * 256;        // 1024 v elems
    const int hh = i >> 6;
    const int d = i & 63;
    Vt[(((size_t)bb * NHEADS + hh) * HD + d) * SP + s] = row[2048 + i];
  }
}

// ---------------------------------------------------------------------------
// Causal MFMA flash attention, 1 wave per (b, h, 16-query tile).
// ---------------------------------------------------------------------------
__global__ __launch_bounds__(64)
void attn_k(const short* __restrict__ Q, const short* __restrict__ Kt,
            const short* __restrict__ Vt, short* __restrict__ O)
{
  const int qt = blockIdx.x;   // 0..16
  const int hh = blockIdx.y;
  const int bb = blockIdx.z;
  const int lane = threadIdx.x;
  const int r16 = lane & 15;
  const int quad = lane >> 4;

  const size_t bh = (size_t)bb * NHEADS + hh;
  const short* qbase = Q  + bh * SP * HD;
  const short* kbase = Kt + bh * SP * HD;
  const short* vbase = Vt + bh * HD * SP;

  const int qrow_l = qt * 16 + r16;
  const short8 qf0 = *(const short8*)(qbase + qrow_l * HD + quad * 8);
  const short8 qf1 = *(const short8*)(qbase + qrow_l * HD + 32 + quad * 8);

  float m_i[4], l_i[4];
  f32x4 oacc[4];
#pragma unroll
  for (int r = 0; r < 4; ++r) { m_i[r] = -INFINITY; l_i[r] = 0.f; }
#pragma unroll
  for (int t = 0; t < 4; ++t) oacc[t] = (f32x4){0.f, 0.f, 0.f, 0.f};

  __shared__ float pls[16][33];

  const int nkb = qt / 2 + 1;
  for (int kbi = 0; kbi < nkb; ++kbi) {
    const int key0 = kbi * 32 + r16;
    const int key1 = key0 + 16;
    const short8 kf00 = *(const short8*)(kbase + key0 * HD + quad * 8);
    const short8 kf01 = *(const short8*)(kbase + key0 * HD + 32 + quad * 8);
    const short8 kf10 = *(const short8*)(kbase + key1 * HD + quad * 8);
    const short8 kf11 = *(const short8*)(kbase + key1 * HD + 32 + quad * 8);

    f32x4 s0 = (f32x4){0.f, 0.f, 0.f, 0.f};
    f32x4 s1 = (f32x4){0.f, 0.f, 0.f, 0.f};
    s0 = __builtin_amdgcn_mfma_f32_16x16x32_bf16(qf0, kf00, s0, 0, 0, 0);
    s0 = __builtin_amdgcn_mfma_f32_16x16x32_bf16(qf1, kf01, s0, 0, 0, 0);
    s1 = __builtin_amdgcn_mfma_f32_16x16x32_bf16(qf0, kf10, s1, 0, 0, 0);
    s1 = __builtin_amdgcn_mfma_f32_16x16x32_bf16(qf1, kf11, s1, 0, 0, 0);

    const int col0 = kbi * 32 + r16;
    const int col1 = col0 + 16;
    float p0[4], p1[4];
#pragma unroll
    for (int r = 0; r < 4; ++r) {
      const int qrow = qt * 16 + quad * 4 + r;
      float v0 = (col0 <= qrow) ? s0[r] * 0.125f : -INFINITY;
      float v1 = (col1 <= qrow) ? s1[r] * 0.125f : -INFINITY;
      float mx = fmaxf(v0, v1);
#pragma unroll
      for (int off = 1; off < 16; off <<= 1)
        mx = fmaxf(mx, __shfl_xor(mx, off, 64));
      const float mnew = fmaxf(m_i[r], mx);
      const float alpha = __expf(m_i[r] - mnew);
      m_i[r] = mnew;
      p0[r] = __expf(v0 - mnew);
      p1[r] = __expf(v1 - mnew);
      float rs = p0[r] + p1[r];
#pragma unroll
      for (int off = 1; off < 16; off <<= 1)
        rs += __shfl_xor(rs, off, 64);
      l_i[r] = l_i[r] * alpha + rs;
#pragma unroll
      for (int t = 0; t < 4; ++t) oacc[t][r] *= alpha;
    }

    // transpose P (C-layout) -> A-layout through LDS
    __syncthreads();
#pragma unroll
    for (int r = 0; r < 4; ++r) {
      pls[quad * 4 + r][r16]      = p0[r];
      pls[quad * 4 + r][16 + r16] = p1[r];
    }
    __syncthreads();
    short8 pf;
#pragma unroll
    for (int j = 0; j < 8; ++j) pf[j] = f2bs(pls[r16][quad * 8 + j]);

#pragma unroll
    for (int t = 0; t < 4; ++t) {
      const short8 vf = *(const short8*)(vbase + (t * 16 + r16) * SP + kbi * 32 + quad * 8);
      oacc[t] = __builtin_amdgcn_mfma_f32_16x16x32_bf16(pf, vf, oacc[t], 0, 0, 0);
    }
  }

#pragma unroll
  for (int r = 0; r < 4; ++r) {
    const int qrow = qt * 16 + quad * 4 + r;
    if (qrow >= SEQT) continue;
    const float inv = 1.f / l_i[r];
#pragma unroll
    for (int t = 0; t < 4; ++t)
      O[((size_t)(bb * SEQT + qrow)) * EMBED + hh * HD + t * 16 + r16] = f2bs(oacc[t][r] * inv);
  }
}

// ---------------------------------------------------------------------------
extern "C" void kernel_launch(void* const* d_in, const int* in_sizes, int n_in,
                              void* d_out, int out_size, void* d_ws, size_t ws_size,
                              hipStream_t stream)
{
  (void)in_sizes; (void)n_in; (void)out_size; (void)ws_size;
  const float* x      = (const float*)d_in[0];
  const float* cond   = (const float*)d_in[1];
  const float* patchW = (const float*)d_in[2];
  const float* patchB = (const float*)d_in[3];
  const float* lnG    = (const float*)d_in[4];
  const float* lnB    = (const float*)d_in[5];
  const float* posE   = (const float*)d_in[6];
  const float* condW  = (const float*)d_in[7];
  const float* condB  = (const float*)d_in[8];
  const float* wqkv   = (const float*)d_in[9];
  const float* wo     = (const float*)d_in[10];
  const float* w1     = (const float*)d_in[11];
  const float* w2     = (const float*)d_in[12];
  const float* w3     = (const float*)d_in[13];
  const float* anw    = (const float*)d_in[14];
  const float* fnw    = (const float*)d_in[15];

  char* p = (char*)d_ws;
  auto alloc = [&](size_t bytes) -> void* {
    void* r = (void*)p;
    p += (bytes + 255) & ~(size_t)255;
    return r;
  };

  short* wqkvT = (short*)alloc((size_t)NBLK * 3072 * 1024 * 2);
  short* woT   = (short*)alloc((size_t)NBLK * 1024 * 1024 * 2);
  short* w1T   = (short*)alloc((size_t)NBLK * HIDF * 1024 * 2);
  short* w2T   = (short*)alloc((size_t)NBLK * 1024 * HIDF * 2);
  short* w3T   = (short*)alloc((size_t)NBLK * HIDF * 1024 * 2);
  short* pwT   = (short*)alloc((size_t)1024 * 768 * 2);
  short* xb    = (short*)alloc((size_t)8192 * 768 * 2);
  float* tmp   = (float*)alloc((size_t)8192 * 1024 * 4);
  float* cemb  = (float*)alloc((size_t)32 * 1024 * 4);
  float* hbuf  = (float*)alloc((size_t)MPAD * 1024 * 4);
  short* abuf  = (short*)alloc((size_t)MPAD * 1024 * 2);
  short* qkvb  = (short*)alloc((size_t)MPAD * 3072 * 2);
  short* qb    = (short*)alloc((size_t)BATCH * NHEADS * SP * HD * 2);
  short* kbuf  = (short*)alloc((size_t)BATCH * NHEADS * SP * HD * 2);
  short* vtb   = (short*)alloc((size_t)BATCH * NHEADS * HD * SP * 2);
  short* ob    = (short*)alloc((size_t)MPAD * 1024 * 2);
  short* u3b   = (short*)alloc((size_t)MPAD * HIDF * 2);
  short* gbuf  = (short*)alloc((size_t)MPAD * HIDF * 2);
  float* fc    = (float*)alloc((size_t)SEQT * 32 * 2 * 4);

  const dim3 tb32(32, 8);
  for (int l = 0; l < NBLK; ++l) {
    transpose_cast<<<dim3(3072 / 32, 1024 / 32), tb32, 0, stream>>>(
        wqkv + (size_t)l * 1024 * 3072, wqkvT + (size_t)l * 3072 * 1024, 1024, 3072);
    transpose_cast<<<dim3(1024 / 32, 1024 / 32), tb32, 0, stream>>>(
        wo + (size_t)l * 1024 * 1024, woT + (size_t)l * 1024 * 1024, 1024, 1024);
    transpose_cast<<<dim3(HIDF / 32, 1024 / 32), tb32, 0, stream>>>(
        w1 + (size_t)l * 1024 * HIDF, w1T + (size_t)l * HIDF * 1024, 1024, HIDF);
    transpose_cast<<<dim3(1024 / 32, HIDF / 32), tb32, 0, stream>>>(
        w2 + (size_t)l * HIDF * 1024, w2T + (size_t)l * 1024 * HIDF, HIDF, 1024);
    transpose_cast<<<dim3(HIDF / 32, 1024 / 32), tb32, 0, stream>>>(
        w3 + (size_t)l * 1024 * HIDF, w3T + (size_t)l * HIDF * 1024, 1024, HIDF);
  }
  transpose_cast<<<dim3(1024 / 32, 768 / 32), tb32, 0, stream>>>(patchW, pwT, 768, 1024);
  cast_bf16<<<(8192 * 768 + 255) / 256, 256, 0, stream>>>(x, xb, 8192 * 768);
  freqs_k<<<(SEQT * 32 + 255) / 256, 256, 0, stream>>>(fc);
  cond_embed_k<<<dim3(4, 32), 256, 0, stream>>>(cond, condW, condB, cemb);
  gemm_bt<1><<<dim3(1024 / 128, 8192 / 128), 256, 0, stream>>>(
      xb, pwT, tmp, nullptr, nullptr, 8192, 1024, 768, 8192);
  assemble_ln_k<<<MV, 256, 0, stream>>>(tmp, cemb, patchB, posE, lnG, lnB, hbuf);

  for (int l = 0; l < NBLK; ++l) {
    rmsnorm_k<<<MV, 256, 0, stream>>>(hbuf, anw + l * 1024, abuf);
    gemm_bt<0><<<dim3(3072 / 128, MPAD / 128), 256, 0, stream>>>(
        abuf, wqkvT + (size_t)l * 3072 * 1024, qkvb, nullptr, nullptr, MPAD, 3072, 1024, MV);
    rope_k<<<MV, 256, 0, stream>>>(qkvb, fc, qb, kbuf, vtb);
    attn_k<<<dim3(17, NHEADS, BATCH), 64, 0, stream>>>(qb, kbuf, vtb, ob);
    gemm_bt<2><<<dim3(1024 / 128, MPAD / 128), 256, 0, stream>>>(
        ob, woT + (size_t)l * 1024 * 1024, hbuf, hbuf, nullptr, MPAD, 1024, 1024, MV);
    rmsnorm_k<<<MV, 256, 0, stream>>>(hbuf, fnw + l * 1024, abuf);
    gemm_bt<0><<<dim3(HIDF / 128, MPAD / 128), 256, 0, stream>>>(
        abuf, w3T + (size_t)l * HIDF * 1024, u3b, nullptr, nullptr, MPAD, HIDF, 1024, MV);
    gemm_bt<3><<<dim3(HIDF / 128, MPAD / 128), 256, 0, stream>>>(
        abuf, w1T + (size_t)l * HIDF * 1024, gbuf, nullptr, u3b, MPAD, HIDF, 1024, MV);
    float* outp = (l == NBLK - 1) ? (float*)d_out : hbuf;
    gemm_bt<2><<<dim3(1024 / 128, MPAD / 128), 256, 0, stream>>>(
        gbuf, w2T + (size_t)l * 1024 * HIDF, outp, hbuf, nullptr, MPAD, 1024, HIDF, MV);
  }
}

// Round 2
// 5835.769 us; speedup vs baseline: 1.1129x; 1.1129x over previous
//
#include <hip/hip_runtime.h>
#include <hip/hip_bf16.h>
#include <cstdint>
#include <cstddef>

// Problem constants
#define NBLK   12
#define EMBED  1024
#define SEQT   257          // tokens incl CLS
#define BATCH  32
#define NHEADS 16
#define HD     64
#define HIDF   2816
#define MV     (BATCH*SEQT) // 8224 valid rows
#define MPAD   8320         // 65*128
#define SP     288          // padded seq for attention (9*32)

typedef __attribute__((ext_vector_type(8))) short short8;
typedef __attribute__((ext_vector_type(4))) float f32x4;

__device__ __forceinline__ short f2bs(float f) {
  unsigned u = __float_as_uint(f);
  unsigned r = (u + 0x7fffu + ((u >> 16) & 1u)) >> 16;
  return (short)r;
}
__device__ __forceinline__ float bs2f(short s) {
  return __uint_as_float(((unsigned)(unsigned short)s) << 16);
}

__device__ __forceinline__ void async_copy16(void* lds, const void* g) {
  __builtin_amdgcn_global_load_lds(
      (const __attribute__((address_space(1))) unsigned int*)g,
      (__attribute__((address_space(3))) unsigned int*)lds,
      16, 0, 0);
}

// ---------------------------------------------------------------------------
// Generic bf16 GEMM, A [M][K] row-major, B^T [N][K] row-major, 128x128 tile,
// BK=64, 4 waves each computing 64x64 via 4x4 grid of 16x16x32 MFMAs.
// LDS layout XOR-swizzled: physical 16B-chunk = logical_chunk ^ (row & 7),
// inverse applied to global addresses during global_load_lds staging
// (LDS dest is wave-uniform base + lane*16, so we permute the source).
// MODE 0: store bf16; 1: store f32; 2: f32 + residual add; 3: silu(C)*Aux bf16
// ---------------------------------------------------------------------------
template<int MODE>
__global__ __launch_bounds__(256, 2)
void gemm_bt(const short* __restrict__ A, const short* __restrict__ B,
             void* __restrict__ Out, const float* __restrict__ Resid,
             const short* __restrict__ Aux,
             int M, int N, int K, int Mvalid)
{
  __shared__ short sA[128 * 64];
  __shared__ short sB[128 * 64];
  const int tid  = threadIdx.x;
  const int wid  = tid >> 6;
  const int lane = tid & 63;
  const int r16  = lane & 15;
  const int quad = lane >> 4;

  // grouped block swizzle: consecutive blocks walk GROUP_M M-tiles per N-tile
  const int nTn = gridDim.x, nTm = gridDim.y;
  const int pid = blockIdx.y * nTn + blockIdx.x;
  const int GROUP_M = 8;
  const int group_size = GROUP_M * nTn;
  const int group_id = pid / group_size;
  const int first_m = group_id * GROUP_M;
  const int gsz = min(GROUP_M, nTm - first_m);
  const int pid_m = first_m + (pid % group_size) % gsz;
  const int pid_n = (pid % group_size) / gsz;
  const int m0 = pid_m * 128;
  const int n0 = pid_n * 128;

  const int wm = (wid >> 1) * 64;
  const int wn = (wid & 1) * 64;

  f32x4 acc[4][4];
#pragma unroll
  for (int i = 0; i < 4; ++i)
#pragma unroll
    for (int j = 0; j < 4; ++j)
      acc[i][j] = (f32x4){0.f, 0.f, 0.f, 0.f};

  const int nk = K >> 6;
  for (int kt = 0; kt < nk; ++kt) {
    const int k0 = kt << 6;
    __syncthreads();   // all waves done reading previous tile
#pragma unroll
    for (int i = 0; i < 4; ++i) {
      const int cbase = wid * 256 + i * 64;   // wave-uniform chunk base
      const int s   = cbase + lane;           // this lane's physical 16B slot
      const int row = s >> 3;                 // 8 chunks per 64-elem row
      const int cc  = (s & 7) ^ (row & 7);    // logical chunk for this slot
      async_copy16(&sA[cbase * 8], A + (size_t)(m0 + row) * K + k0 + cc * 8);
      async_copy16(&sB[cbase * 8], B + (size_t)(n0 + row) * K + k0 + cc * 8);
    }
    asm volatile("s_waitcnt vmcnt(0)" ::: "memory");
    __syncthreads();
#pragma unroll
    for (int ks = 0; ks < 2; ++ks) {
      short8 af[4], bf[4];
      const int cbase_l = ks * 4 + quad;       // logical chunk of this frag
      const int cphys = cbase_l ^ (r16 & 7);   // row&7 == r16&7 (wm,t*16 are ×16)
#pragma unroll
      for (int t = 0; t < 4; ++t) {
        af[t] = *(const short8*)&sA[(wm + t * 16 + r16) * 64 + cphys * 8];
        bf[t] = *(const short8*)&sB[(wn + t * 16 + r16) * 64 + cphys * 8];
      }
#pragma unroll
      for (int i = 0; i < 4; ++i)
#pragma unroll
        for (int j = 0; j < 4; ++j)
          acc[i][j] = __builtin_amdgcn_mfma_f32_16x16x32_bf16(af[i], bf[j], acc[i][j], 0, 0, 0);
    }
  }

#pragma unroll
  for (int i = 0; i < 4; ++i) {
#pragma unroll
    for (int r = 0; r < 4; ++r) {
      const int row = m0 + wm + i * 16 + quad * 4 + r;
      if (row >= Mvalid) continue;
#pragma unroll
      for (int j = 0; j < 4; ++j) {
        const int col = n0 + wn + j * 16 + r16;
        const size_t idx = (size_t)row * N + col;
        const float v = acc[i][j][r];
        if (MODE == 0) {
          ((short*)Out)[idx] = f2bs(v);
        } else if (MODE == 1) {
          ((float*)Out)[idx] = v;
        } else if (MODE == 2) {
          ((float*)Out)[idx] = v + Resid[idx];
        } else {
          const float u3 = bs2f(Aux[idx]);
          const float sig = 1.f / (1.f + __expf(-v));
          ((short*)Out)[idx] = f2bs(v * sig * u3);
        }
      }
    }
  }
}

// ---------------------------------------------------------------------------
// fp32 [K][N] -> bf16 [N][K] transpose+cast (32x32 LDS tile), batched over z
// ---------------------------------------------------------------------------
__global__ void transpose_cast(const float* __restrict__ src, short* __restrict__ dst,
                               int K, int N)
{
  const size_t loff = (size_t)blockIdx.z * (size_t)K * N;
  src += loff; dst += loff;
  __shared__ float t[32][33];
  const int n0 = blockIdx.x * 32;
  const int k0 = blockIdx.y * 32;
  const int tx = threadIdx.x;
  const int ty = threadIdx.y;  // 0..7
#pragma unroll
  for (int i = 0; i < 32; i += 8)
    t[ty + i][tx] = src[(size_t)(k0 + ty + i) * N + n0 + tx];
  __syncthreads();
#pragma unroll
  for (int i = 0; i < 32; i += 8)
    dst[(size_t)(n0 + ty + i) * K + k0 + tx] = f2bs(t[tx][ty + i]);
}

__global__ void cast_bf16(const float* __restrict__ src, short* __restrict__ dst, int n)
{
  const int i = blockIdx.x * 256 + threadIdx.x;
  if (i < n) dst[i] = f2bs(src[i]);
}

// ---------------------------------------------------------------------------
// RoPE cos/sin table: fc[s][j][0/1], s in [0,257), j in [0,32). s=0 -> zeros.
// ---------------------------------------------------------------------------
__global__ void freqs_k(float* __restrict__ fc)
{
  const int idx = blockIdx.x * 256 + threadIdx.x;
  if (idx >= SEQT * 32) return;
  const int s = idx >> 5;
  const int j = idx & 31;
  float c = 0.f, sn = 0.f;
  if (s != 0) {
    const int p = s - 1;
    const int pos = (j < 16) ? (p >> 4) : (p & 15);
    const int fi = (j < 16) ? j : (j - 16);
    const float fr = __powf(10000.f, -(float)fi / 16.f);
    const float ang = (float)pos * fr;
    c = cosf(ang); sn = sinf(ang);
  }
  fc[idx * 2]     = c;
  fc[idx * 2 + 1] = sn;
}

// ---------------------------------------------------------------------------
// cond embed: c[b][o] = cond[b] . cond_w[:,o] + cond_b[o]   (fp32 exact)
// ---------------------------------------------------------------------------
__global__ void cond_embed_k(const float* __restrict__ cond, const float* __restrict__ w,
                             const float* __restrict__ bias, float* __restrict__ out)
{
  const int b = blockIdx.y;
  const int o = blockIdx.x * 256 + threadIdx.x;
  const float* cr = cond + (size_t)b * EMBED;
  float acc = 0.f;
  for (int in = 0; in < 1024; ++in)
    acc += cr[in] * w[(size_t)in * EMBED + o];
  out[(size_t)b * EMBED + o] = acc + bias[o];
}

// ---------------------------------------------------------------------------
// Assemble token row (cond token / patch+bias) + pos_embed, then LayerNorm.
// ---------------------------------------------------------------------------
__global__ void assemble_ln_k(const float* __restrict__ tmp, const float* __restrict__ cemb,
                              const float* __restrict__ pb, const float* __restrict__ pos,
                              const float* __restrict__ g, const float* __restrict__ beta,
                              float* __restrict__ h)
{
  const int r = blockIdx.x;
  const int bb = r / SEQT;
  const int s = r % SEQT;
  const int t = threadIdx.x;
  float4 v;
  if (s == 0) {
    v = ((const float4*)(cemb + (size_t)bb * EMBED))[t];
  } else {
    v = ((const float4*)(tmp + (size_t)(bb * 256 + s - 1) * EMBED))[t];
    const float4 pb4 = ((const float4*)pb)[t];
    v.x += pb4.x; v.y += pb4.y; v.z += pb4.z; v.w += pb4.w;
  }
  const float4 p4 = ((const float4*)(pos + (size_t)s * EMBED))[t];
  v.x += p4.x; v.y += p4.y; v.z += p4.z; v.w += p4.w;

  float s1 = v.x + v.y + v.z + v.w;
  float s2 = v.x * v.x + v.y * v.y + v.z * v.z + v.w * v.w;
  __shared__ float sb[8];
  const int lane = t & 63, wid = t >> 6;
#pragma unroll
  for (int off = 32; off > 0; off >>= 1) {
    s1 += __shfl_down(s1, off, 64);
    s2 += __shfl_down(s2, off, 64);
  }
  if (lane == 0) { sb[wid] = s1; sb[4 + wid] = s2; }
  __syncthreads();
  const float tot   = sb[0] + sb[1] + sb[2] + sb[3];
  const float totsq = sb[4] + sb[5] + sb[6] + sb[7];
  const float mean = tot * (1.f / 1024.f);
  const float var  = totsq * (1.f / 1024.f) - mean * mean;
  const float sc = rsqrtf(var + 1e-6f);
  const float4 g4 = ((const float4*)g)[t];
  const float4 be4 = ((const float4*)beta)[t];
  float4 o;
  o.x = (v.x - mean) * sc * g4.x + be4.x;
  o.y = (v.y - mean) * sc * g4.y + be4.y;
  o.z = (v.z - mean) * sc * g4.z + be4.z;
  o.w = (v.w - mean) * sc * g4.w + be4.w;
  ((float4*)(h + (size_t)r * EMBED))[t] = o;
}

// ---------------------------------------------------------------------------
// RMSNorm fp32 row -> bf16 (x * rsqrt(mean(x^2)+eps)) * w
// ---------------------------------------------------------------------------
__global__ void rmsnorm_k(const float* __restrict__ h, const float* __restrict__ w,
                          short* __restrict__ out)
{
  const int r = blockIdx.x;
  const int t = threadIdx.x;
  const float4 v = ((const float4*)(h + (size_t)r * EMBED))[t];
  float ss = v.x * v.x + v.y * v.y + v.z * v.z + v.w * v.w;
  __shared__ float sb[4];
  const int lane = t & 63, wid = t >> 6;
#pragma unroll
  for (int off = 32; off > 0; off >>= 1) ss += __shfl_down(ss, off, 64);
  if (lane == 0) sb[wid] = ss;
  __syncthreads();
  const float tot = sb[0] + sb[1] + sb[2] + sb[3];
  const float sc = rsqrtf(tot * (1.f / 1024.f) + 1e-5f);
  const float4 w4 = ((const float4*)w)[t];
  short* op = out + (size_t)r * EMBED + t * 4;
  op[0] = f2bs(v.x * sc * w4.x);
  op[1] = f2bs(v.y * sc * w4.y);
  op[2] = f2bs(v.z * sc * w4.z);
  op[3] = f2bs(v.w * sc * w4.w);
}

// ---------------------------------------------------------------------------
// RoPE + scatter into per-head Q [bh][SP][64], K [bh][SP][64], V^T [bh][64][SP]
// ---------------------------------------------------------------------------
__global__ void rope_k(const short* __restrict__ qkv, const float* __restrict__ fc,
                       short* __restrict__ Q, short* __restrict__ Kt, short* __restrict__ Vt)
{
  const int r = blockIdx.x;
  const int bb = r / SEQT;
  const int s = r % SEQT;
  const int t = threadIdx.x;
  const short* row = qkv + (size_t)r * 3072;
#pragma unroll
  for (int ii = 0; ii < 2; ++ii) {
    const int i = t + ii * 256;        // 512 (head,pair) combos
    const int hh = i >> 5;
    const int j = i & 31;
    const float cs = fc[(s * 32 + j) * 2];
    const float sn = fc[(s * 32 + j) * 2 + 1];
    const size_t ob = (((size_t)bb * NHEADS + hh) * SP + s) * HD + 2 * j;
    {
      const float x0 = bs2f(row[hh * HD + 2 * j]);
      const float x1 = bs2f(row[hh * HD + 2 * j + 1]);
      Q[ob]     = f2bs(x0 * cs - x1 * sn);
      Q[ob + 1] = f2bs(x1 * cs + x0 * sn);
    }
    {
      const float x0 = bs2f(row[EMBED + hh * HD + 2 * j]);
      const float x1 = bs2f(row[EMBED + hh * HD + 2 * j + 1]);
      Kt[ob]     = f2bs(x0 * cs - x1 * sn);
      Kt[ob + 1] = f2bs(x1 * cs + x0 * sn);
    }
  }
#pragma unroll
  for (int ii = 0; ii < 4; ++ii) {
    const int i = t + ii * 256;        // 1024 v elems
    const int hh = i >> 6;
    const int d = i & 63;
    Vt[(((size_t)bb * NHEADS + hh) * HD + d) * SP + s] = row[2048 + i];
  }
}

// ---------------------------------------------------------------------------
// Causal MFMA flash attention, 1 wave per (b, h, 16-query tile).
// ---------------------------------------------------------------------------
__global__ __launch_bounds__(64)
void attn_k(const short* __restrict__ Q, const short* __restrict__ Kt,
            const short* __restrict__ Vt, short* __restrict__ O)
{
  const int qt = blockIdx.x;   // 0..16
  const int hh = blockIdx.y;
  const int bb = blockIdx.z;
  const int lane = threadIdx.x;
  const int r16 = lane & 15;
  const int quad = lane >> 4;

  const size_t bh = (size_t)bb * NHEADS + hh;
  const short* qbase = Q  + bh * SP * HD;
  const short* kbase = Kt + bh * SP * HD;
  const short* vbase = Vt + bh * HD * SP;

  const int qrow_l = qt * 16 + r16;
  const short8 qf0 = *(const short8*)(qbase + qrow_l * HD + quad * 8);
  const short8 qf1 = *(const short8*)(qbase + qrow_l * HD + 32 + quad * 8);

  float m_i[4], l_i[4];
  f32x4 oacc[4];
#pragma unroll
  for (int r = 0; r < 4; ++r) { m_i[r] = -INFINITY; l_i[r] = 0.f; }
#pragma unroll
  for (int t = 0; t < 4; ++t) oacc[t] = (f32x4){0.f, 0.f, 0.f, 0.f};

  __shared__ float pls[16][33];

  const int nkb = qt / 2 + 1;
  for (int kbi = 0; kbi < nkb; ++kbi) {
    const int key0 = kbi * 32 + r16;
    const int key1 = key0 + 16;
    const short8 kf00 = *(const short8*)(kbase + key0 * HD + quad * 8);
    const short8 kf01 = *(const short8*)(kbase + key0 * HD + 32 + quad * 8);
    const short8 kf10 = *(const short8*)(kbase + key1 * HD + quad * 8);
    const short8 kf11 = *(const short8*)(kbase + key1 * HD + 32 + quad * 8);

    f32x4 s0 = (f32x4){0.f, 0.f, 0.f, 0.f};
    f32x4 s1 = (f32x4){0.f, 0.f, 0.f, 0.f};
    s0 = __builtin_amdgcn_mfma_f32_16x16x32_bf16(qf0, kf00, s0, 0, 0, 0);
    s0 = __builtin_amdgcn_mfma_f32_16x16x32_bf16(qf1, kf01, s0, 0, 0, 0);
    s1 = __builtin_amdgcn_mfma_f32_16x16x32_bf16(qf0, kf10, s1, 0, 0, 0);
    s1 = __builtin_amdgcn_mfma_f32_16x16x32_bf16(qf1, kf11, s1, 0, 0, 0);

    const int col0 = kbi * 32 + r16;
    const int col1 = col0 + 16;
    float p0[4], p1[4];
#pragma unroll
    for (int r = 0; r < 4; ++r) {
      const int qrow = qt * 16 + quad * 4 + r;
      float v0 = (col0 <= qrow) ? s0[r] * 0.125f : -INFINITY;
      float v1 = (col1 <= qrow) ? s1[r] * 0.125f : -INFINITY;
      float mx = fmaxf(v0, v1);
#pragma unroll
      for (int off = 1; off < 16; off <<= 1)
        mx = fmaxf(mx, __shfl_xor(mx, off, 64));
      const float mnew = fmaxf(m_i[r], mx);
      const float alpha = __expf(m_i[r] - mnew);
      m_i[r] = mnew;
      p0[r] = __expf(v0 - mnew);
      p1[r] = __expf(v1 - mnew);
      float rs = p0[r] + p1[r];
#pragma unroll
      for (int off = 1; off < 16; off <<= 1)
        rs += __shfl_xor(rs, off, 64);
      l_i[r] = l_i[r] * alpha + rs;
#pragma unroll
      for (int t = 0; t < 4; ++t) oacc[t][r] *= alpha;
    }

    // transpose P (C-layout) -> A-layout through LDS
    __syncthreads();
#pragma unroll
    for (int r = 0; r < 4; ++r) {
      pls[quad * 4 + r][r16]      = p0[r];
      pls[quad * 4 + r][16 + r16] = p1[r];
    }
    __syncthreads();
    short8 pf;
#pragma unroll
    for (int j = 0; j < 8; ++j) pf[j] = f2bs(pls[r16][quad * 8 + j]);

#pragma unroll
    for (int t = 0; t < 4; ++t) {
      const short8 vf = *(const short8*)(vbase + (t * 16 + r16) * SP + kbi * 32 + quad * 8);
      oacc[t] = __builtin_amdgcn_mfma_f32_16x16x32_bf16(pf, vf, oacc[t], 0, 0, 0);
    }
  }

#pragma unroll
  for (int r = 0; r < 4; ++r) {
    const int qrow = qt * 16 + quad * 4 + r;
    if (qrow >= SEQT) continue;
    const float inv = 1.f / l_i[r];
#pragma unroll
    for (int t = 0; t < 4; ++t)
      O[((size_t)(bb * SEQT + qrow)) * EMBED + hh * HD + t * 16 + r16] = f2bs(oacc[t][r] * inv);
  }
}

// ---------------------------------------------------------------------------
extern "C" void kernel_launch(void* const* d_in, const int* in_sizes, int n_in,
                              void* d_out, int out_size, void* d_ws, size_t ws_size,
                              hipStream_t stream)
{
  (void)in_sizes; (void)n_in; (void)out_size; (void)ws_size;
  const float* x      = (const float*)d_in[0];
  const float* cond   = (const float*)d_in[1];
  const float* patchW = (const float*)d_in[2];
  const float* patchB = (const float*)d_in[3];
  const float* lnG    = (const float*)d_in[4];
  const float* lnB    = (const float*)d_in[5];
  const float* posE   = (const float*)d_in[6];
  const float* condW  = (const float*)d_in[7];
  const float* condB  = (const float*)d_in[8];
  const float* wqkv   = (const float*)d_in[9];
  const float* wo     = (const float*)d_in[10];
  const float* w1     = (const float*)d_in[11];
  const float* w2     = (const float*)d_in[12];
  const float* w3     = (const float*)d_in[13];
  const float* anw    = (const float*)d_in[14];
  const float* fnw    = (const float*)d_in[15];

  char* p = (char*)d_ws;
  auto alloc = [&](size_t bytes) -> void* {
    void* r = (void*)p;
    p += (bytes + 255) & ~(size_t)255;
    return r;
  };

  short* wqkvT = (short*)alloc((size_t)NBLK * 3072 * 1024 * 2);
  short* woT   = (short*)alloc((size_t)NBLK * 1024 * 1024 * 2);
  short* w1T   = (short*)alloc((size_t)NBLK * HIDF * 1024 * 2);
  short* w2T   = (short*)alloc((size_t)NBLK * 1024 * HIDF * 2);
  short* w3T   = (short*)alloc((size_t)NBLK * HIDF * 1024 * 2);
  short* pwT   = (short*)alloc((size_t)1024 * 768 * 2);
  short* xb    = (short*)alloc((size_t)8192 * 768 * 2);
  float* tmp   = (float*)alloc((size_t)8192 * 1024 * 4);
  float* cemb  = (float*)alloc((size_t)32 * 1024 * 4);
  float* hbuf  = (float*)alloc((size_t)MPAD * 1024 * 4);
  short* abuf  = (short*)alloc((size_t)MPAD * 1024 * 2);
  short* qkvb  = (short*)alloc((size_t)MPAD * 3072 * 2);
  short* qb    = (short*)alloc((size_t)BATCH * NHEADS * SP * HD * 2);
  short* kbuf  = (short*)alloc((size_t)BATCH * NHEADS * SP * HD * 2);
  short* vtb   = (short*)alloc((size_t)BATCH * NHEADS * HD * SP * 2);
  short* ob    = (short*)alloc((size_t)MPAD * 1024 * 2);
  short* u3b   = (short*)alloc((size_t)MPAD * HIDF * 2);
  short* gbuf  = (short*)alloc((size_t)MPAD * HIDF * 2);
  float* fc    = (float*)alloc((size_t)SEQT * 32 * 2 * 4);

  const dim3 tb32(32, 8);
  transpose_cast<<<dim3(3072 / 32, 1024 / 32, NBLK), tb32, 0, stream>>>(wqkv, wqkvT, 1024, 3072);
  transpose_cast<<<dim3(1024 / 32, 1024 / 32, NBLK), tb32, 0, stream>>>(wo, woT, 1024, 1024);
  transpose_cast<<<dim3(HIDF / 32, 1024 / 32, NBLK), tb32, 0, stream>>>(w1, w1T, 1024, HIDF);
  transpose_cast<<<dim3(1024 / 32, HIDF / 32, NBLK), tb32, 0, stream>>>(w2, w2T, HIDF, 1024);
  transpose_cast<<<dim3(HIDF / 32, 1024 / 32, NBLK), tb32, 0, stream>>>(w3, w3T, 1024, HIDF);
  transpose_cast<<<dim3(1024 / 32, 768 / 32, 1), tb32, 0, stream>>>(patchW, pwT, 768, 1024);
  cast_bf16<<<(8192 * 768 + 255) / 256, 256, 0, stream>>>(x, xb, 8192 * 768);
  freqs_k<<<(SEQT * 32 + 255) / 256, 256, 0, stream>>>(fc);
  cond_embed_k<<<dim3(4, 32), 256, 0, stream>>>(cond, condW, condB, cemb);
  gemm_bt<1><<<dim3(1024 / 128, 8192 / 128), 256, 0, stream>>>(
      xb, pwT, tmp, nullptr, nullptr, 8192, 1024, 768, 8192);
  assemble_ln_k<<<MV, 256, 0, stream>>>(tmp, cemb, patchB, posE, lnG, lnB, hbuf);

  for (int l = 0; l < NBLK; ++l) {
    rmsnorm_k<<<MV, 256, 0, stream>>>(hbuf, anw + l * 1024, abuf);
    gemm_bt<0><<<dim3(3072 / 128, MPAD / 128), 256, 0, stream>>>(
        abuf, wqkvT + (size_t)l * 3072 * 1024, qkvb, nullptr, nullptr, MPAD, 3072, 1024, MV);
    rope_k<<<MV, 256, 0, stream>>>(qkvb, fc, qb, kbuf, vtb);
    attn_k<<<dim3(17, NHEADS, BATCH), 64, 0, stream>>>(qb, kbuf, vtb, ob);
    gemm_bt<2><<<dim3(1024 / 128, MPAD / 128), 256, 0, stream>>>(
        ob, woT + (size_t)l * 1024 * 1024, hbuf, hbuf, nullptr, MPAD, 1024, 1024, MV);
    rmsnorm_k<<<MV, 256, 0, stream>>>(hbuf, fnw + l * 1024, abuf);
    gemm_bt<0><<<dim3(HIDF / 128, MPAD / 128), 256, 0, stream>>>(
        abuf, w3T + (size_t)l * HIDF * 1024, u3b, nullptr, nullptr, MPAD, HIDF, 1024, MV);
    gemm_bt<3><<<dim3(HIDF / 128, MPAD / 128), 256, 0, stream>>>(
        abuf, w1T + (size_t)l * HIDF * 1024, gbuf, nullptr, u3b, MPAD, HIDF, 1024, MV);
    float* outp = (l == NBLK - 1) ? (float*)d_out : hbuf;
    gemm_bt<2><<<dim3(1024 / 128, MPAD / 128), 256, 0, stream>>>(
        gbuf, w2T + (size_t)l * 1024 * HIDF, outp, hbuf, nullptr, MPAD, 1024, HIDF, MV);
  }
}